// Round 13
// baseline (195.041 us; speedup 1.0000x reference)
//
#include <hip/hip_runtime.h>
#include <hip/hip_bf16.h>

typedef unsigned int   u32;
typedef unsigned short u16;

typedef __attribute__((ext_vector_type(8))) short    sh8;
typedef __attribute__((ext_vector_type(4))) float    f32x4;
typedef __attribute__((ext_vector_type(4))) _Float16 f16x4;
typedef __attribute__((ext_vector_type(8))) _Float16 f16x8;
typedef __attribute__((ext_vector_type(2))) _Float16 f16x2;
typedef __attribute__((ext_vector_type(2))) __fp16   fp16x2raw;

union F16x8 { f16x8 v; uint4 u; f16x2 p[4]; _Float16 h[8]; };
union F16x4u { uint2 u; _Float16 h[4]; };
union CvtU  { fp16x2raw r; f16x2 p; u32 u; };

__device__ __forceinline__ float b2f(u16 u) { union { u32 i; float f; } v; v.i = ((u32)u) << 16; return v.f; }
__device__ __forceinline__ u16   f2b(float f){
  union { float f; u32 i; } v; v.f = f;
  u32 u = v.i;
  u32 r = (u + 0x7fffu + ((u >> 16) & 1u)) >> 16;   // RNE
  return (u16)r;
}
// pack two f32 -> bf16x2 (RNE), lo half = a, hi half = b
__device__ __forceinline__ u32 pk2(float a, float b) {
  __hip_bfloat162 h2 = __float22bfloat162_rn(make_float2(a, b));
  union { __hip_bfloat162 h; u32 u; } v; v.h = h2; return v.u;
}
__device__ __forceinline__ f16x2 cvtpk(float a, float b) {
  CvtU c; c.r = __builtin_amdgcn_cvt_pkrtz(a, b); return c.p;
}
__device__ __forceinline__ u32 cvtpku(float a, float b) {
  CvtU c; c.r = __builtin_amdgcn_cvt_pkrtz(a, b); return c.u;
}

__device__ __forceinline__ f32x4 mfma16(uint4 a, uint4 b, f32x4 c) {
  union { uint4 u; sh8 s; } ua, ub;
  ua.u = a; ub.u = b;
  return __builtin_amdgcn_mfma_f32_16x16x32_bf16(ua.s, ub.s, c, 0, 0, 0);
}
__device__ __forceinline__ f32x4 mfma32h(f16x8 a, f16x8 b, f32x4 c) {
  return __builtin_amdgcn_mfma_f32_16x16x32_f16(a, b, c, 0, 0, 0);
}

// split 8 consecutive f32 (one lane's K-chunk) into bf16 hi/lo operand words
__device__ __forceinline__ void split8(float4 v0, float4 v1, uint4& hi, uint4& lo) {
  float a[8] = {v0.x, v0.y, v0.z, v0.w, v1.x, v1.y, v1.z, v1.w};
  u32 hw[4], lw[4];
#pragma unroll
  for (int t = 0; t < 4; t++) {
    u32 hp = pk2(a[2 * t], a[2 * t + 1]);
    float r0 = a[2 * t]     - __uint_as_float(hp << 16);
    float r1 = a[2 * t + 1] - __uint_as_float(hp & 0xffff0000u);
    hw[t] = hp;
    lw[t] = pk2(r0, r1);
  }
  hi = make_uint4(hw[0], hw[1], hw[2], hw[3]);
  lo = make_uint4(lw[0], lw[1], lw[2], lw[3]);
}

// ---------------------------------------------------------------------------
// gemm_mf: two independent C = A @ B^T f32 GEMMs via MFMA (sel = by>>4).
// One wave per 16x16 C tile.  Used for the output projections (N=256, K=256).
// ---------------------------------------------------------------------------
__global__ void __launch_bounds__(256)
gemm_mf(const float* __restrict__ A0, const float* __restrict__ B0, float* __restrict__ C0,
        const float* __restrict__ A1, const float* __restrict__ B1, float* __restrict__ C1,
        int N, int K) {
  int t = threadIdx.x, L = t & 63, w = t >> 6;
  int cl = L & 15, q = L >> 4;
  int by = blockIdx.y, sel = by >> 4;
  const float* A  = sel ? A1 : A0;
  const float* Bw = sel ? B1 : B0;
  float*       C  = sel ? C1 : C0;
  int m0 = (by & 15) * 64 + w * 16;
  int n0 = blockIdx.x * 16;

  f32x4 acc; acc[0] = 0.f; acc[1] = 0.f; acc[2] = 0.f; acc[3] = 0.f;
  const float* ar = A  + (size_t)(m0 + cl) * K + 8 * q;
  const float* br = Bw + (size_t)(n0 + cl) * K + 8 * q;

  for (int k0 = 0; k0 < K; k0 += 32) {
    float4 av0 = *(const float4*)(ar + k0);
    float4 av1 = *(const float4*)(ar + k0 + 4);
    float4 bv0 = *(const float4*)(br + k0);
    float4 bv1 = *(const float4*)(br + k0 + 4);
    uint4 ahi, alo, bhi, blo;
    split8(av0, av1, ahi, alo);
    split8(bv0, bv1, bhi, blo);
    acc = mfma16(ahi, bhi, acc);
    acc = mfma16(ahi, blo, acc);
    acc = mfma16(alo, bhi, acc);
  }
#pragma unroll
  for (int i = 0; i < 4; i++)
    C[(size_t)(m0 + 4 * q + i) * N + n0 + cl] = acc[i];
}

// ---------------------------------------------------------------------------
// gemm_mf_pack: QKV projections (N=512, K=256) with FUSED fragment packing.
// by<32: gemm.  n0>=256 -> V stored f16 [b][row][256] (via Ld transpose).
// n0<256 (h = bx): Q/K tile transposed in per-wave LDS, emitted as frags.
// by==32, bx<8: W1 (bf16 hi/lo) + W2 (f16x8 paired-nt mapping) packing.
// ---------------------------------------------------------------------------
__global__ void __launch_bounds__(256)
gemm_mf_pack(const float* __restrict__ x1, const float* __restrict__ Wqv1, u16* __restrict__ vh1,
             const float* __restrict__ x2, const float* __restrict__ Wkv2, u16* __restrict__ vh2,
             const float* __restrict__ W1, const float* __restrict__ W2,
             uint4* __restrict__ QQ4, uint4* __restrict__ KH4, uint4* __restrict__ KL4z,
             uint4* __restrict__ W1Bhi, uint4* __restrict__ W1Blo,
             uint4* __restrict__ W2F8hi, uint4* __restrict__ W2F8lo) {
  __shared__ float Ld[4][16][17];
  int t = threadIdx.x, L = t & 63, w = t >> 6;
  int cl = L & 15, q = L >> 4;
  int by = blockIdx.y;

  if (by == 32) {                       // ---- W packing blocks ----
    if (blockIdx.x >= 8) return;
    int tid = blockIdx.x * 256 + t;     // 0..2047
    if (tid < 1024) {
      int LL = tid & 63;
      int j = (tid >> 6) * 16 + (LL & 15), qq = LL >> 4;
      u32 hw[4] = {0,0,0,0}, lw[4] = {0,0,0,0};
#pragma unroll
      for (int jj = 0; jj < 8; jj++) {
        float wv = W1[j * 32 + qq * 8 + jj];
        u16 hb = f2b(wv); u16 lb = f2b(wv - b2f(hb));
        hw[jj >> 1] |= ((u32)hb) << (16 * (jj & 1));
        lw[jj >> 1] |= ((u32)lb) << (16 * (jj & 1));
      }
      W1Bhi[tid] = make_uint4(hw[0], hw[1], hw[2], hw[3]);
      W1Blo[tid] = make_uint4(lw[0], lw[1], lw[2], lw[3]);
    } else if (tid < 1536) {
      int t2 = tid - 1024;              // p*64 + L
      int LL = t2 & 63, p = t2 >> 6;
      int h = LL & 15, qq = LL >> 4;
      F16x8 hi, lo;
#pragma unroll
      for (int jj = 0; jj < 8; jj++) {
        int j = 32 * p + ((jj >> 2) << 4) + 4 * qq + (jj & 3);
        float wv = W2[h * 256 + j];
        hi.h[jj] = (_Float16)wv;
        lo.h[jj] = (_Float16)(wv - (float)hi.h[jj]);
      }
      W2F8hi[t2] = hi.u;
      W2F8lo[t2] = lo.u;
    }
    return;
  }

  int sel = by >> 4;
  const float* A  = sel ? x2 : x1;
  const float* Bw = sel ? Wkv2 : Wqv1;
  int m0 = (by & 15) * 64 + w * 16;
  int n0 = blockIdx.x * 16;

  f32x4 acc; acc[0] = 0.f; acc[1] = 0.f; acc[2] = 0.f; acc[3] = 0.f;
  const float* ar = A  + (size_t)(m0 + cl) * 256 + 8 * q;
  const float* br = Bw + (size_t)(n0 + cl) * 256 + 8 * q;

  for (int k0 = 0; k0 < 256; k0 += 32) {
    float4 av0 = *(const float4*)(ar + k0);
    float4 av1 = *(const float4*)(ar + k0 + 4);
    float4 bv0 = *(const float4*)(br + k0);
    float4 bv1 = *(const float4*)(br + k0 + 4);
    uint4 ahi, alo, bhi, blo;
    split8(av0, av1, ahi, alo);
    split8(bv0, bv1, bhi, blo);
    acc = mfma16(ahi, bhi, acc);
    acc = mfma16(ahi, blo, acc);
    acc = mfma16(alo, bhi, acc);
  }

  int b = m0 >> 9;
  int row = (m0 & 511) + cl;            // r (or c) index after transpose

  if (n0 >= 256) {                      // ---- V half: f16 store via transpose ----
#pragma unroll
    for (int i = 0; i < 4; i++) Ld[w][cl][4 * q + i] = acc[i];
    if (q < 2) {
      float v[8];
#pragma unroll
      for (int jj = 0; jj < 8; jj++) v[jj] = Ld[w][q * 8 + jj][cl];
      uint4 o = make_uint4(cvtpku(v[0], v[1]), cvtpku(v[2], v[3]),
                           cvtpku(v[4], v[5]), cvtpku(v[6], v[7]));
      u16* vh = sel ? vh2 : vh1;
      *(uint4*)(vh + ((size_t)(b * 512) + row) * 256 + (n0 - 256) + q * 8) = o;
    }
    return;
  }

  // ---- Q/K half: per-wave 16x16 transpose, then fragment emit ----
#pragma unroll
  for (int i = 0; i < 4; i++) Ld[w][cl][4 * q + i] = acc[i];   // Ld[d][r_local]
  float v[8];
#pragma unroll
  for (int jj = 0; jj < 8; jj++) v[jj] = Ld[w][(q & 1) * 8 + jj][cl];

  int r = row;
  int h = n0 >> 4;                      // == blockIdx.x

  if (sel == 0) {                       // Q: x0.25 folded; q<2 hi, q>=2 lo
    u32 wv[4];
#pragma unroll
    for (int t2 = 0; t2 < 4; t2++) {
      float a  = v[2 * t2] * 0.25f, bb = v[2 * t2 + 1] * 0.25f;
      u32 hp = pk2(a, bb);
      if (q >= 2) {
        float r0 = a  - __uint_as_float(hp << 16);
        float r1 = bb - __uint_as_float(hp & 0xffff0000u);
        wv[t2] = pk2(r0, r1);
      } else wv[t2] = hp;
    }
    QQ4[((size_t)((b * 16 + h) * 4 + q) << 9) + r] = make_uint4(wv[0], wv[1], wv[2], wv[3]);
  } else {                              // K: hi + lo + zero slots
    u32 hw[4], lw[4];
#pragma unroll
    for (int t2 = 0; t2 < 4; t2++) {
      float a = v[2 * t2], bb = v[2 * t2 + 1];
      u32 hp = pk2(a, bb);
      float r0 = a  - __uint_as_float(hp << 16);
      float r1 = bb - __uint_as_float(hp & 0xffff0000u);
      hw[t2] = hp;
      lw[t2] = pk2(r0, r1);
    }
    if (q < 2) {
      KH4[((size_t)((b * 16 + h) * 2 + q) << 9) + r]       = make_uint4(hw[0], hw[1], hw[2], hw[3]);
      KL4z[((size_t)((b * 16 + h) * 4 + 2 + q) << 9) + r]  = make_uint4(0, 0, 0, 0);
    } else {
      KL4z[((size_t)((b * 16 + h) * 4 + (q - 2)) << 9) + r] = make_uint4(lw[0], lw[1], lw[2], lw[3]);
    }
  }
}

// ---------------------------------------------------------------------------
// ms_mfma7: all-MFMA fused QK^T + MixedScoreFF.  Phase B processes r in TWO
// halves of 8: xhi[8]/xlo[8] (64 VGPR) are built once per half and genuinely
// fit in registers (r12's xhi[16]/xlo[16]=128 VGPR forced the compiler to
// rematerialize X from LDS every p-iteration -> VALU-bound).  Weights loaded
// per p (16 total p-iterations), acc2[16] lives in AGPRs.
// ---------------------------------------------------------------------------
__global__ void __launch_bounds__(256, 2)
ms_mfma7(const uint4* __restrict__ QQ4, const uint4* __restrict__ KH4,
         const uint4* __restrict__ KL4z, const float* __restrict__ cost,
         const uint4* __restrict__ W1Bhi, const uint4* __restrict__ W1Blo,
         const uint4* __restrict__ W2F8hi, const uint4* __restrict__ W2F8lo,
         u16* __restrict__ ms1, u16* __restrict__ ms2) {
  __shared__ __align__(16) u32 Dl[4 * 4160];
  int t = threadIdx.x, L = t & 63, w = t >> 6;
  int cl = L & 15, q = L >> 4;
  int b = blockIdx.z, c0 = blockIdx.x * 16, r0 = (blockIdx.y * 4 + w) * 16;
  u32* D = Dl + w * 4160;

  f32x4 z; z[0] = 0.f; z[1] = 0.f; z[2] = 0.f; z[3] = 0.f;

  // ---- phase A: QK^T (scaled) via MFMA, 16 heads -> D[h][r][c] in LDS ----
#pragma unroll 2
  for (int h = 0; h < 16; h++) {
    uint4 qa  = QQ4[((size_t)((b * 16 + h) * 4 + q) << 9) + r0 + cl];       // [qh|ql]
    uint4 qa2 = QQ4[((size_t)((b * 16 + h) * 4 + (q & 1)) << 9) + r0 + cl]; // [qh|qh]
    uint4 kb1 = KH4[((size_t)((b * 16 + h) * 2 + (q & 1)) << 9) + c0 + cl]; // [kh|kh]
    uint4 kb2 = KL4z[((size_t)((b * 16 + h) * 4 + q) << 9) + c0 + cl];      // [kl|0]
    f32x4 d = mfma16(qa, kb1, z);
    d = mfma16(qa2, kb2, d);
#pragma unroll
    for (int i = 0; i < 4; i++)
      D[h * 260 + (q * 4 + i) * 16 + cl] = __float_as_uint(d[i]);
  }

  f32x4 acc2[16];
#pragma unroll
  for (int r = 0; r < 16; r++) acc2[r] = z;

  // ---- phase B: two r-halves; X-frags in regs per half; p-outer MLP ----
#pragma unroll 1
  for (int half = 0; half < 2; half++) {
    uint4 xhi[8], xlo[8];
#pragma unroll
    for (int rr = 0; rr < 8; rr++) {
      int r = half * 8 + rr;
      float cvm = cost[((size_t)(b * 512) + r0 + r) * 512 + c0 + cl];
      u32 cp = pk2(cvm, cvm);
      float cres = cvm - __uint_as_float(cp & 0xffff0000u);
      u32 hw[4], lw[4];
#pragma unroll
      for (int tt = 0; tt < 4; tt++) {
        float dd = __uint_as_float(D[(4 * q + tt) * 260 + r * 16 + cl]);
        u32 hp = pk2(dd, cvm);
        float dres = dd - __uint_as_float(hp << 16);
        hw[tt] = hp;
        lw[tt] = pk2(dres, cres);
      }
      xhi[rr] = make_uint4(hw[0], hw[1], hw[2], hw[3]);
      xlo[rr] = make_uint4(lw[0], lw[1], lw[2], lw[3]);
    }

#pragma unroll 1
    for (int p = 0; p < 8; p++) {
      uint4 w1h0 = W1Bhi[(2 * p) * 64 + L],     w1l0 = W1Blo[(2 * p) * 64 + L];
      uint4 w1h1 = W1Bhi[(2 * p + 1) * 64 + L], w1l1 = W1Blo[(2 * p + 1) * 64 + L];
      F16x8 w2h, w2l;
      w2h.u = W2F8hi[p * 64 + L];
      w2l.u = W2F8lo[p * 64 + L];
#pragma unroll
      for (int rr = 0; rr < 8; rr++) {
        int r = half * 8 + rr;
        f32x4 a0 = z, a1 = z;
        a0 = mfma16(w1h0, xhi[rr], a0);
        a0 = mfma16(w1h0, xlo[rr], a0);
        a0 = mfma16(w1l0, xhi[rr], a0);
        a1 = mfma16(w1h1, xhi[rr], a1);
        a1 = mfma16(w1h1, xlo[rr], a1);
        a1 = mfma16(w1l1, xhi[rr], a1);
        F16x8 hf;
        hf.p[0] = cvtpk(fmaxf(a0[0], 0.f), fmaxf(a0[1], 0.f));
        hf.p[1] = cvtpk(fmaxf(a0[2], 0.f), fmaxf(a0[3], 0.f));
        hf.p[2] = cvtpk(fmaxf(a1[0], 0.f), fmaxf(a1[1], 0.f));
        hf.p[3] = cvtpk(fmaxf(a1[2], 0.f), fmaxf(a1[3], 0.f));
        acc2[r] = mfma32h(hf.v, w2h.v, acc2[r]);
        acc2[r] = mfma32h(hf.v, w2l.v, acc2[r]);
      }
    }
  }

  // ---- epilogue: lane (q,cl) holds MS[h=cl][c=c0+4q+i][r0..r0+15] ----
  u32* ms1u = (u32*)ms1;
#pragma unroll
  for (int r = 0; r < 16; r++) {
    size_t base = ((size_t)(b * 16 + cl) * 512 + (r0 + r)) * 256 + (c0 >> 1) + q * 2;
    ms1u[base]     = pk2(acc2[r][0], acc2[r][1]);
    ms1u[base + 1] = pk2(acc2[r][2], acc2[r][3]);
  }
  u32* ms2u = (u32*)ms2;
#pragma unroll
  for (int i = 0; i < 4; i++) {
    int c = c0 + 4 * q + i;
    u32 o[8];
#pragma unroll
    for (int rr = 0; rr < 8; rr++)
      o[rr] = pk2(acc2[2 * rr][i], acc2[2 * rr + 1][i]);
    size_t base2 = ((size_t)(b * 16 + cl) * 512 + c) * 256 + (r0 >> 1);
    *(uint4*)&ms2u[base2]     = make_uint4(o[0], o[1], o[2], o[3]);
    *(uint4*)&ms2u[base2 + 4] = make_uint4(o[4], o[5], o[6], o[7]);
  }
}

// ---------------------------------------------------------------------------
// softmax_all5: both directions (dir = blockIdx.z); block = (b, 4 fix rows).
// p stored f16 in swizzled LDS [cc][(h+cc)&15][f] -> phase B reads all 4 f
// values with ONE ds_read_b64 (conflict-free).  V read f16 (vh buffers).
// ---------------------------------------------------------------------------
__global__ void __launch_bounds__(256)
softmax_all5(const u16* __restrict__ ms1s, const u16* __restrict__ ms2s,
             const int* __restrict__ mask,
             const u16* __restrict__ vh1, const u16* __restrict__ vh2,
             float* __restrict__ o1, float* __restrict__ o2) {
  __shared__ _Float16 pbuf[512 * 16 * 4];   // [cc][(h+cc)&15][f]  64 KB
  __shared__ float    sden[4][16];
  __shared__ float4   red[4][64];
  int t = threadIdx.x, lane = t & 63, w = t >> 6;
  int fix0 = blockIdx.x * 4, b = blockIdx.y, dir = blockIdx.z;
  const u16* ms   = dir ? ms2s : ms1s;
  const u16* vbuf = dir ? vh1 : vh2;
  float*     obuf = dir ? o2 : o1;

  // ---- phase A: wave w handles fix = fix0 + w ----
  int fix = fix0 + w;
  bool vd[8];
#pragma unroll
  for (int i = 0; i < 8; i++) {
    int cc = i * 64 + lane;
    int mv = dir ? mask[((size_t)b * 512 + cc) * 512 + fix]
                 : mask[((size_t)b * 512 + fix) * 512 + cc];
    vd[i] = mv != 0;
  }
  bool anyl = false;
#pragma unroll
  for (int i = 0; i < 8; i++) anyl |= vd[i];
  bool useMask = (__ballot(anyl) != 0ULL);   // fully-masked row => unmask all

#pragma unroll 2
  for (int h = 0; h < 16; h++) {
    const u16* mrow = ms + ((size_t)(b * 16 + h) * 512 + fix) * 512;
    float lg[8];
#pragma unroll
    for (int i = 0; i < 8; i++) lg[i] = b2f(mrow[i * 64 + lane]);
    float mx = -3.4e38f;
#pragma unroll
    for (int i = 0; i < 8; i++)
      if (!(useMask && !vd[i])) mx = fmaxf(mx, lg[i]);
    for (int off = 32; off; off >>= 1) mx = fmaxf(mx, __shfl_xor(mx, off));
    float s = 0.f;
#pragma unroll
    for (int i = 0; i < 8; i++) {
      float p = (useMask && !vd[i]) ? 0.f : __expf(lg[i] - mx);
      int cc = i * 64 + lane;
      pbuf[(cc * 16 + ((h + cc) & 15)) * 4 + w] = (_Float16)p;
      s += p;
    }
    for (int off = 32; off; off >>= 1) s += __shfl_xor(s, off);
    if (lane == 0) sden[w][h] = s;
  }
  __syncthreads();

  // ---- phase B: thread (w, hb=lane>>2, dq=lane&3) accumulates cc = 4*it+w ----
  int hb = lane >> 2, dq = lane & 3;
  const u16* vb = vbuf + (size_t)b * 131072 + hb * 16 + dq * 4;
  float4 acc[4];
#pragma unroll
  for (int f = 0; f < 4; f++) acc[f] = make_float4(0.f, 0.f, 0.f, 0.f);
  for (int it = 0; it < 128; it++) {
    int cc = it * 4 + w;
    F16x4u vv; vv.u = *(const uint2*)(vb + (size_t)cc * 256);
    F16x4u pv; pv.u = *(const uint2*)&pbuf[(cc * 16 + ((hb + cc) & 15)) * 4];
    float v0 = (float)vv.h[0], v1 = (float)vv.h[1];
    float v2 = (float)vv.h[2], v3 = (float)vv.h[3];
#pragma unroll
    for (int f = 0; f < 4; f++) {
      float p = (float)pv.h[f];
      acc[f].x += p * v0; acc[f].y += p * v1;
      acc[f].z += p * v2; acc[f].w += p * v3;
    }
  }
#pragma unroll 1
  for (int f = 0; f < 4; f++) {
    red[w][lane] = acc[f];
    __syncthreads();
    if (w == 0) {
      float4 s0 = red[0][lane], s1 = red[1][lane];
      float4 s2 = red[2][lane], s3 = red[3][lane];
      float inv = 1.f / sden[f][hb];
      float4 o;
      o.x = (s0.x + s1.x + s2.x + s3.x) * inv;
      o.y = (s0.y + s1.y + s2.y + s3.y) * inv;
      o.z = (s0.z + s1.z + s2.z + s3.z) * inv;
      o.w = (s0.w + s1.w + s2.w + s3.w) * inv;
      *(float4*)(obuf + ((size_t)b * 512 + fix0 + f) * 256 + lane * 4) = o;
    }
    __syncthreads();
  }
}

// ---------------------------------------------------------------------------
extern "C" void kernel_launch(void* const* d_in, const int* in_sizes, int n_in,
                              void* d_out, int out_size, void* d_ws, size_t ws_size,
                              hipStream_t stream) {
  const float* x1    = (const float*)d_in[0];
  const float* x2    = (const float*)d_in[1];
  const int*   attn  = (const int*)d_in[2];
  const float* cost  = (const float*)d_in[3];
  const float* Wqv1  = (const float*)d_in[4];
  const float* Wkv2  = (const float*)d_in[5];
  const float* W1    = (const float*)d_in[6];
  const float* W2    = (const float*)d_in[7];
  const float* Wout1 = (const float*)d_in[8];
  const float* Wout2 = (const float*)d_in[9];
  float* out = (float*)d_out;

  char* ws = (char*)d_ws;
  uint4* W1Bhi  = (uint4*)(ws);                              // 16 KB
  uint4* W1Blo  = (uint4*)(ws + (16 << 10));                 // 16 KB
  uint4* W2F8hi = (uint4*)(ws + (32 << 10));                 //  8 KB
  uint4* W2F8lo = (uint4*)(ws + (40 << 10));                 //  8 KB
  u16*   vh1 = (u16*)(ws + (64 << 10));                      // 512 KB [b][r][256] f16 (v1)
  u16*   vh2 = (u16*)(ws + (64 << 10) + (512 << 10));        // 512 KB [b][c][256] f16 (v2)
  u16*   ms1 = (u16*)(ws + (64 << 10) + (4 << 20));          //  16 MB [b][h][r][c]
  u16*   ms2 = (u16*)(ws + (64 << 10) + (20 << 20));         //  16 MB [b][h][c][r]
  char*  tail= (ws + (64 << 10) + (36 << 20));
  uint4* QQ4  = (uint4*)(tail);                              //   1 MB
  uint4* KH4  = (uint4*)(tail + (1 << 20));                  // 0.5 MB
  uint4* KL4z = (uint4*)(tail + (1 << 20) + (512 << 10));    //   1 MB
  float* o1  = (float*)(tail + (3 << 20));                   //   1 MB [b][r][256]
  float* o2  = (float*)(tail + (4 << 20));                   //   1 MB [b][c][256]

  gemm_mf_pack<<<dim3(32, 33), 256, 0, stream>>>(x1, Wqv1, vh1, x2, Wkv2, vh2,
                                                 W1, W2, QQ4, KH4, KL4z,
                                                 W1Bhi, W1Blo, W2F8hi, W2F8lo);

  ms_mfma7<<<dim3(32, 8, 2), 256, 0, stream>>>(QQ4, KH4, KL4z, cost,
                                               W1Bhi, W1Blo, W2F8hi, W2F8lo, ms1, ms2);

  softmax_all5<<<dim3(128, 2, 2), 256, 0, stream>>>(ms1, ms2, attn, vh1, vh2, o1, o2);

  gemm_mf<<<dim3(16, 32), 256, 0, stream>>>(o1, Wout1, out, o2, Wout2, out + (size_t)262144, 256, 256);
}

// Round 14
// 177.195 us; speedup vs baseline: 1.1007x; 1.1007x over previous
//
#include <hip/hip_runtime.h>
#include <hip/hip_bf16.h>

typedef unsigned int   u32;
typedef unsigned short u16;

typedef __attribute__((ext_vector_type(8))) short    sh8;
typedef __attribute__((ext_vector_type(4))) float    f32x4;
typedef __attribute__((ext_vector_type(4))) _Float16 f16x4;
typedef __attribute__((ext_vector_type(8))) _Float16 f16x8;
typedef __attribute__((ext_vector_type(2))) _Float16 f16x2;
typedef __attribute__((ext_vector_type(2))) __fp16   fp16x2raw;

union F16x8 { f16x8 v; uint4 u; f16x2 p[4]; _Float16 h[8]; };
union F16x4u { uint2 u; _Float16 h[4]; };
union CvtU  { fp16x2raw r; f16x2 p; u32 u; };

__device__ __forceinline__ float b2f(u16 u) { union { u32 i; float f; } v; v.i = ((u32)u) << 16; return v.f; }
__device__ __forceinline__ u16   f2b(float f){
  union { float f; u32 i; } v; v.f = f;
  u32 u = v.i;
  u32 r = (u + 0x7fffu + ((u >> 16) & 1u)) >> 16;   // RNE
  return (u16)r;
}
// pack two f32 -> bf16x2 (RNE), lo half = a, hi half = b
__device__ __forceinline__ u32 pk2(float a, float b) {
  __hip_bfloat162 h2 = __float22bfloat162_rn(make_float2(a, b));
  union { __hip_bfloat162 h; u32 u; } v; v.h = h2; return v.u;
}
__device__ __forceinline__ f16x2 cvtpk(float a, float b) {
  CvtU c; c.r = __builtin_amdgcn_cvt_pkrtz(a, b); return c.p;
}
__device__ __forceinline__ u32 cvtpku(float a, float b) {
  CvtU c; c.r = __builtin_amdgcn_cvt_pkrtz(a, b); return c.u;
}

__device__ __forceinline__ f32x4 mfma16(uint4 a, uint4 b, f32x4 c) {
  union { uint4 u; sh8 s; } ua, ub;
  ua.u = a; ub.u = b;
  return __builtin_amdgcn_mfma_f32_16x16x32_bf16(ua.s, ub.s, c, 0, 0, 0);
}
__device__ __forceinline__ f32x4 mfma32h(f16x8 a, f16x8 b, f32x4 c) {
  return __builtin_amdgcn_mfma_f32_16x16x32_f16(a, b, c, 0, 0, 0);
}

// split 8 consecutive f32 (one lane's K-chunk) into bf16 hi/lo operand words
__device__ __forceinline__ void split8(float4 v0, float4 v1, uint4& hi, uint4& lo) {
  float a[8] = {v0.x, v0.y, v0.z, v0.w, v1.x, v1.y, v1.z, v1.w};
  u32 hw[4], lw[4];
#pragma unroll
  for (int t = 0; t < 4; t++) {
    u32 hp = pk2(a[2 * t], a[2 * t + 1]);
    float r0 = a[2 * t]     - __uint_as_float(hp << 16);
    float r1 = a[2 * t + 1] - __uint_as_float(hp & 0xffff0000u);
    hw[t] = hp;
    lw[t] = pk2(r0, r1);
  }
  hi = make_uint4(hw[0], hw[1], hw[2], hw[3]);
  lo = make_uint4(lw[0], lw[1], lw[2], lw[3]);
}

// ---------------------------------------------------------------------------
// gemm_mf: two independent C = A @ B^T f32 GEMMs via MFMA (sel = by>>4).
// One wave per 16x16 C tile.  Used for the output projections (N=256, K=256).
// ---------------------------------------------------------------------------
__global__ void __launch_bounds__(256)
gemm_mf(const float* __restrict__ A0, const float* __restrict__ B0, float* __restrict__ C0,
        const float* __restrict__ A1, const float* __restrict__ B1, float* __restrict__ C1,
        int N, int K) {
  int t = threadIdx.x, L = t & 63, w = t >> 6;
  int cl = L & 15, q = L >> 4;
  int by = blockIdx.y, sel = by >> 4;
  const float* A  = sel ? A1 : A0;
  const float* Bw = sel ? B1 : B0;
  float*       C  = sel ? C1 : C0;
  int m0 = (by & 15) * 64 + w * 16;
  int n0 = blockIdx.x * 16;

  f32x4 acc; acc[0] = 0.f; acc[1] = 0.f; acc[2] = 0.f; acc[3] = 0.f;
  const float* ar = A  + (size_t)(m0 + cl) * K + 8 * q;
  const float* br = Bw + (size_t)(n0 + cl) * K + 8 * q;

  for (int k0 = 0; k0 < K; k0 += 32) {
    float4 av0 = *(const float4*)(ar + k0);
    float4 av1 = *(const float4*)(ar + k0 + 4);
    float4 bv0 = *(const float4*)(br + k0);
    float4 bv1 = *(const float4*)(br + k0 + 4);
    uint4 ahi, alo, bhi, blo;
    split8(av0, av1, ahi, alo);
    split8(bv0, bv1, bhi, blo);
    acc = mfma16(ahi, bhi, acc);
    acc = mfma16(ahi, blo, acc);
    acc = mfma16(alo, bhi, acc);
  }
#pragma unroll
  for (int i = 0; i < 4; i++)
    C[(size_t)(m0 + 4 * q + i) * N + n0 + cl] = acc[i];
}

// ---------------------------------------------------------------------------
// gemm_mf_pack: QKV projections (N=512, K=256) with FUSED fragment packing.
// by<32: gemm.  n0>=256 -> V stored f16 [b][row][256] (via Ld transpose).
// n0<256 (h = bx): Q/K tile transposed in per-wave LDS, emitted as frags.
// by==32, bx<8: W1 (bf16 hi/lo) + W2 (f16x8 paired-nt mapping) packing.
// ---------------------------------------------------------------------------
__global__ void __launch_bounds__(256)
gemm_mf_pack(const float* __restrict__ x1, const float* __restrict__ Wqv1, u16* __restrict__ vh1,
             const float* __restrict__ x2, const float* __restrict__ Wkv2, u16* __restrict__ vh2,
             const float* __restrict__ W1, const float* __restrict__ W2,
             uint4* __restrict__ QQ4, uint4* __restrict__ KH4, uint4* __restrict__ KL4z,
             uint4* __restrict__ W1Bhi, uint4* __restrict__ W1Blo,
             uint4* __restrict__ W2F8hi, uint4* __restrict__ W2F8lo) {
  __shared__ float Ld[4][16][17];
  int t = threadIdx.x, L = t & 63, w = t >> 6;
  int cl = L & 15, q = L >> 4;
  int by = blockIdx.y;

  if (by == 32) {                       // ---- W packing blocks ----
    if (blockIdx.x >= 8) return;
    int tid = blockIdx.x * 256 + t;     // 0..2047
    if (tid < 1024) {
      int LL = tid & 63;
      int j = (tid >> 6) * 16 + (LL & 15), qq = LL >> 4;
      u32 hw[4] = {0,0,0,0}, lw[4] = {0,0,0,0};
#pragma unroll
      for (int jj = 0; jj < 8; jj++) {
        float wv = W1[j * 32 + qq * 8 + jj];
        u16 hb = f2b(wv); u16 lb = f2b(wv - b2f(hb));
        hw[jj >> 1] |= ((u32)hb) << (16 * (jj & 1));
        lw[jj >> 1] |= ((u32)lb) << (16 * (jj & 1));
      }
      W1Bhi[tid] = make_uint4(hw[0], hw[1], hw[2], hw[3]);
      W1Blo[tid] = make_uint4(lw[0], lw[1], lw[2], lw[3]);
    } else if (tid < 1536) {
      int t2 = tid - 1024;              // p*64 + L
      int LL = t2 & 63, p = t2 >> 6;
      int h = LL & 15, qq = LL >> 4;
      F16x8 hi, lo;
#pragma unroll
      for (int jj = 0; jj < 8; jj++) {
        int j = 32 * p + ((jj >> 2) << 4) + 4 * qq + (jj & 3);
        float wv = W2[h * 256 + j];
        hi.h[jj] = (_Float16)wv;
        lo.h[jj] = (_Float16)(wv - (float)hi.h[jj]);
      }
      W2F8hi[t2] = hi.u;
      W2F8lo[t2] = lo.u;
    }
    return;
  }

  int sel = by >> 4;
  const float* A  = sel ? x2 : x1;
  const float* Bw = sel ? Wkv2 : Wqv1;
  int m0 = (by & 15) * 64 + w * 16;
  int n0 = blockIdx.x * 16;

  f32x4 acc; acc[0] = 0.f; acc[1] = 0.f; acc[2] = 0.f; acc[3] = 0.f;
  const float* ar = A  + (size_t)(m0 + cl) * 256 + 8 * q;
  const float* br = Bw + (size_t)(n0 + cl) * 256 + 8 * q;

  for (int k0 = 0; k0 < 256; k0 += 32) {
    float4 av0 = *(const float4*)(ar + k0);
    float4 av1 = *(const float4*)(ar + k0 + 4);
    float4 bv0 = *(const float4*)(br + k0);
    float4 bv1 = *(const float4*)(br + k0 + 4);
    uint4 ahi, alo, bhi, blo;
    split8(av0, av1, ahi, alo);
    split8(bv0, bv1, bhi, blo);
    acc = mfma16(ahi, bhi, acc);
    acc = mfma16(ahi, blo, acc);
    acc = mfma16(alo, bhi, acc);
  }

  int b = m0 >> 9;
  int row = (m0 & 511) + cl;            // r (or c) index after transpose

  if (n0 >= 256) {                      // ---- V half: f16 store via transpose ----
#pragma unroll
    for (int i = 0; i < 4; i++) Ld[w][cl][4 * q + i] = acc[i];
    if (q < 2) {
      float v[8];
#pragma unroll
      for (int jj = 0; jj < 8; jj++) v[jj] = Ld[w][q * 8 + jj][cl];
      uint4 o = make_uint4(cvtpku(v[0], v[1]), cvtpku(v[2], v[3]),
                           cvtpku(v[4], v[5]), cvtpku(v[6], v[7]));
      u16* vh = sel ? vh2 : vh1;
      *(uint4*)(vh + ((size_t)(b * 512) + row) * 256 + (n0 - 256) + q * 8) = o;
    }
    return;
  }

  // ---- Q/K half: per-wave 16x16 transpose, then fragment emit ----
#pragma unroll
  for (int i = 0; i < 4; i++) Ld[w][cl][4 * q + i] = acc[i];   // Ld[d][r_local]
  float v[8];
#pragma unroll
  for (int jj = 0; jj < 8; jj++) v[jj] = Ld[w][(q & 1) * 8 + jj][cl];

  int r = row;
  int h = n0 >> 4;                      // == blockIdx.x

  if (sel == 0) {                       // Q: x0.25 folded; q<2 hi, q>=2 lo
    u32 wv[4];
#pragma unroll
    for (int t2 = 0; t2 < 4; t2++) {
      float a  = v[2 * t2] * 0.25f, bb = v[2 * t2 + 1] * 0.25f;
      u32 hp = pk2(a, bb);
      if (q >= 2) {
        float r0 = a  - __uint_as_float(hp << 16);
        float r1 = bb - __uint_as_float(hp & 0xffff0000u);
        wv[t2] = pk2(r0, r1);
      } else wv[t2] = hp;
    }
    QQ4[((size_t)((b * 16 + h) * 4 + q) << 9) + r] = make_uint4(wv[0], wv[1], wv[2], wv[3]);
  } else {                              // K: hi + lo + zero slots
    u32 hw[4], lw[4];
#pragma unroll
    for (int t2 = 0; t2 < 4; t2++) {
      float a = v[2 * t2], bb = v[2 * t2 + 1];
      u32 hp = pk2(a, bb);
      float r0 = a  - __uint_as_float(hp << 16);
      float r1 = bb - __uint_as_float(hp & 0xffff0000u);
      hw[t2] = hp;
      lw[t2] = pk2(r0, r1);
    }
    if (q < 2) {
      KH4[((size_t)((b * 16 + h) * 2 + q) << 9) + r]       = make_uint4(hw[0], hw[1], hw[2], hw[3]);
      KL4z[((size_t)((b * 16 + h) * 4 + 2 + q) << 9) + r]  = make_uint4(0, 0, 0, 0);
    } else {
      KL4z[((size_t)((b * 16 + h) * 4 + (q - 2)) << 9) + r] = make_uint4(lw[0], lw[1], lw[2], lw[3]);
    }
  }
}

// ---------------------------------------------------------------------------
// ms_mfma7b: all-MFMA fused QK^T + MixedScoreFF.  Phase B processes r in TWO
// FULLY-UNROLLED halves of 8 (r13's `#pragma unroll 1` made `half` runtime ->
// acc2[] runtime-indexed -> scratch spill, 98 MB WRITE_SIZE).  With constant
// indices, xhi/xlo[8] (64 VGPR) + acc2[16] stay in registers.
// ---------------------------------------------------------------------------
__global__ void __launch_bounds__(256, 2)
ms_mfma7b(const uint4* __restrict__ QQ4, const uint4* __restrict__ KH4,
          const uint4* __restrict__ KL4z, const float* __restrict__ cost,
          const uint4* __restrict__ W1Bhi, const uint4* __restrict__ W1Blo,
          const uint4* __restrict__ W2F8hi, const uint4* __restrict__ W2F8lo,
          u16* __restrict__ ms1, u16* __restrict__ ms2) {
  __shared__ __align__(16) u32 Dl[4 * 4160];
  int t = threadIdx.x, L = t & 63, w = t >> 6;
  int cl = L & 15, q = L >> 4;
  int b = blockIdx.z, c0 = blockIdx.x * 16, r0 = (blockIdx.y * 4 + w) * 16;
  u32* D = Dl + w * 4160;

  f32x4 z; z[0] = 0.f; z[1] = 0.f; z[2] = 0.f; z[3] = 0.f;

  // ---- phase A: QK^T (scaled) via MFMA, 16 heads -> D[h][r][c] in LDS ----
#pragma unroll 2
  for (int h = 0; h < 16; h++) {
    uint4 qa  = QQ4[((size_t)((b * 16 + h) * 4 + q) << 9) + r0 + cl];       // [qh|ql]
    uint4 qa2 = QQ4[((size_t)((b * 16 + h) * 4 + (q & 1)) << 9) + r0 + cl]; // [qh|qh]
    uint4 kb1 = KH4[((size_t)((b * 16 + h) * 2 + (q & 1)) << 9) + c0 + cl]; // [kh|kh]
    uint4 kb2 = KL4z[((size_t)((b * 16 + h) * 4 + q) << 9) + c0 + cl];      // [kl|0]
    f32x4 d = mfma16(qa, kb1, z);
    d = mfma16(qa2, kb2, d);
#pragma unroll
    for (int i = 0; i < 4; i++)
      D[h * 260 + (q * 4 + i) * 16 + cl] = __float_as_uint(d[i]);
  }

  f32x4 acc2[16];
#pragma unroll
  for (int r = 0; r < 16; r++) acc2[r] = z;

  // ---- phase B: two fully-unrolled r-halves; X-frags in regs per half ----
#pragma unroll
  for (int half = 0; half < 2; half++) {
    uint4 xhi[8], xlo[8];
#pragma unroll
    for (int rr = 0; rr < 8; rr++) {
      int r = half * 8 + rr;
      float cvm = cost[((size_t)(b * 512) + r0 + r) * 512 + c0 + cl];
      u32 cp = pk2(cvm, cvm);
      float cres = cvm - __uint_as_float(cp & 0xffff0000u);
      u32 hw[4], lw[4];
#pragma unroll
      for (int tt = 0; tt < 4; tt++) {
        float dd = __uint_as_float(D[(4 * q + tt) * 260 + r * 16 + cl]);
        u32 hp = pk2(dd, cvm);
        float dres = dd - __uint_as_float(hp << 16);
        hw[tt] = hp;
        lw[tt] = pk2(dres, cres);
      }
      xhi[rr] = make_uint4(hw[0], hw[1], hw[2], hw[3]);
      xlo[rr] = make_uint4(lw[0], lw[1], lw[2], lw[3]);
    }

#pragma unroll 1
    for (int p = 0; p < 8; p++) {
      uint4 w1h0 = W1Bhi[(2 * p) * 64 + L],     w1l0 = W1Blo[(2 * p) * 64 + L];
      uint4 w1h1 = W1Bhi[(2 * p + 1) * 64 + L], w1l1 = W1Blo[(2 * p + 1) * 64 + L];
      F16x8 w2h, w2l;
      w2h.u = W2F8hi[p * 64 + L];
      w2l.u = W2F8lo[p * 64 + L];
#pragma unroll
      for (int rr = 0; rr < 8; rr++) {
        int r = half * 8 + rr;
        f32x4 a0 = z, a1 = z;
        a0 = mfma16(w1h0, xhi[rr], a0);
        a0 = mfma16(w1h0, xlo[rr], a0);
        a0 = mfma16(w1l0, xhi[rr], a0);
        a1 = mfma16(w1h1, xhi[rr], a1);
        a1 = mfma16(w1h1, xlo[rr], a1);
        a1 = mfma16(w1l1, xhi[rr], a1);
        F16x8 hf;
        hf.p[0] = cvtpk(fmaxf(a0[0], 0.f), fmaxf(a0[1], 0.f));
        hf.p[1] = cvtpk(fmaxf(a0[2], 0.f), fmaxf(a0[3], 0.f));
        hf.p[2] = cvtpk(fmaxf(a1[0], 0.f), fmaxf(a1[1], 0.f));
        hf.p[3] = cvtpk(fmaxf(a1[2], 0.f), fmaxf(a1[3], 0.f));
        acc2[r] = mfma32h(hf.v, w2h.v, acc2[r]);
        acc2[r] = mfma32h(hf.v, w2l.v, acc2[r]);
      }
    }
  }

  // ---- epilogue: lane (q,cl) holds MS[h=cl][c=c0+4q+i][r0..r0+15] ----
  u32* ms1u = (u32*)ms1;
#pragma unroll
  for (int r = 0; r < 16; r++) {
    size_t base = ((size_t)(b * 16 + cl) * 512 + (r0 + r)) * 256 + (c0 >> 1) + q * 2;
    ms1u[base]     = pk2(acc2[r][0], acc2[r][1]);
    ms1u[base + 1] = pk2(acc2[r][2], acc2[r][3]);
  }
  u32* ms2u = (u32*)ms2;
#pragma unroll
  for (int i = 0; i < 4; i++) {
    int c = c0 + 4 * q + i;
    u32 o[8];
#pragma unroll
    for (int rr = 0; rr < 8; rr++)
      o[rr] = pk2(acc2[2 * rr][i], acc2[2 * rr + 1][i]);
    size_t base2 = ((size_t)(b * 16 + cl) * 512 + c) * 256 + (r0 >> 1);
    *(uint4*)&ms2u[base2]     = make_uint4(o[0], o[1], o[2], o[3]);
    *(uint4*)&ms2u[base2 + 4] = make_uint4(o[4], o[5], o[6], o[7]);
  }
}

// ---------------------------------------------------------------------------
// softmax_all5: both directions (dir = blockIdx.z); block = (b, 4 fix rows).
// p stored f16 in swizzled LDS [cc][(h+cc)&15][f] -> phase B reads all 4 f
// values with ONE ds_read_b64 (conflict-free).  V read f16 (vh buffers).
// ---------------------------------------------------------------------------
__global__ void __launch_bounds__(256)
softmax_all5(const u16* __restrict__ ms1s, const u16* __restrict__ ms2s,
             const int* __restrict__ mask,
             const u16* __restrict__ vh1, const u16* __restrict__ vh2,
             float* __restrict__ o1, float* __restrict__ o2) {
  __shared__ _Float16 pbuf[512 * 16 * 4];   // [cc][(h+cc)&15][f]  64 KB
  __shared__ float    sden[4][16];
  __shared__ float4   red[4][64];
  int t = threadIdx.x, lane = t & 63, w = t >> 6;
  int fix0 = blockIdx.x * 4, b = blockIdx.y, dir = blockIdx.z;
  const u16* ms   = dir ? ms2s : ms1s;
  const u16* vbuf = dir ? vh1 : vh2;
  float*     obuf = dir ? o2 : o1;

  // ---- phase A: wave w handles fix = fix0 + w ----
  int fix = fix0 + w;
  bool vd[8];
#pragma unroll
  for (int i = 0; i < 8; i++) {
    int cc = i * 64 + lane;
    int mv = dir ? mask[((size_t)b * 512 + cc) * 512 + fix]
                 : mask[((size_t)b * 512 + fix) * 512 + cc];
    vd[i] = mv != 0;
  }
  bool anyl = false;
#pragma unroll
  for (int i = 0; i < 8; i++) anyl |= vd[i];
  bool useMask = (__ballot(anyl) != 0ULL);   // fully-masked row => unmask all

#pragma unroll 2
  for (int h = 0; h < 16; h++) {
    const u16* mrow = ms + ((size_t)(b * 16 + h) * 512 + fix) * 512;
    float lg[8];
#pragma unroll
    for (int i = 0; i < 8; i++) lg[i] = b2f(mrow[i * 64 + lane]);
    float mx = -3.4e38f;
#pragma unroll
    for (int i = 0; i < 8; i++)
      if (!(useMask && !vd[i])) mx = fmaxf(mx, lg[i]);
    for (int off = 32; off; off >>= 1) mx = fmaxf(mx, __shfl_xor(mx, off));
    float s = 0.f;
#pragma unroll
    for (int i = 0; i < 8; i++) {
      float p = (useMask && !vd[i]) ? 0.f : __expf(lg[i] - mx);
      int cc = i * 64 + lane;
      pbuf[(cc * 16 + ((h + cc) & 15)) * 4 + w] = (_Float16)p;
      s += p;
    }
    for (int off = 32; off; off >>= 1) s += __shfl_xor(s, off);
    if (lane == 0) sden[w][h] = s;
  }
  __syncthreads();

  // ---- phase B: thread (w, hb=lane>>2, dq=lane&3) accumulates cc = 4*it+w ----
  int hb = lane >> 2, dq = lane & 3;
  const u16* vb = vbuf + (size_t)b * 131072 + hb * 16 + dq * 4;
  float4 acc[4];
#pragma unroll
  for (int f = 0; f < 4; f++) acc[f] = make_float4(0.f, 0.f, 0.f, 0.f);
  for (int it = 0; it < 128; it++) {
    int cc = it * 4 + w;
    F16x4u vv; vv.u = *(const uint2*)(vb + (size_t)cc * 256);
    F16x4u pv; pv.u = *(const uint2*)&pbuf[(cc * 16 + ((hb + cc) & 15)) * 4];
    float v0 = (float)vv.h[0], v1 = (float)vv.h[1];
    float v2 = (float)vv.h[2], v3 = (float)vv.h[3];
#pragma unroll
    for (int f = 0; f < 4; f++) {
      float p = (float)pv.h[f];
      acc[f].x += p * v0; acc[f].y += p * v1;
      acc[f].z += p * v2; acc[f].w += p * v3;
    }
  }
#pragma unroll 1
  for (int f = 0; f < 4; f++) {
    red[w][lane] = acc[f];
    __syncthreads();
    if (w == 0) {
      float4 s0 = red[0][lane], s1 = red[1][lane];
      float4 s2 = red[2][lane], s3 = red[3][lane];
      float inv = 1.f / sden[f][hb];
      float4 o;
      o.x = (s0.x + s1.x + s2.x + s3.x) * inv;
      o.y = (s0.y + s1.y + s2.y + s3.y) * inv;
      o.z = (s0.z + s1.z + s2.z + s3.z) * inv;
      o.w = (s0.w + s1.w + s2.w + s3.w) * inv;
      *(float4*)(obuf + ((size_t)b * 512 + fix0 + f) * 256 + lane * 4) = o;
    }
    __syncthreads();
  }
}

// ---------------------------------------------------------------------------
extern "C" void kernel_launch(void* const* d_in, const int* in_sizes, int n_in,
                              void* d_out, int out_size, void* d_ws, size_t ws_size,
                              hipStream_t stream) {
  const float* x1    = (const float*)d_in[0];
  const float* x2    = (const float*)d_in[1];
  const int*   attn  = (const int*)d_in[2];
  const float* cost  = (const float*)d_in[3];
  const float* Wqv1  = (const float*)d_in[4];
  const float* Wkv2  = (const float*)d_in[5];
  const float* W1    = (const float*)d_in[6];
  const float* W2    = (const float*)d_in[7];
  const float* Wout1 = (const float*)d_in[8];
  const float* Wout2 = (const float*)d_in[9];
  float* out = (float*)d_out;

  char* ws = (char*)d_ws;
  uint4* W1Bhi  = (uint4*)(ws);                              // 16 KB
  uint4* W1Blo  = (uint4*)(ws + (16 << 10));                 // 16 KB
  uint4* W2F8hi = (uint4*)(ws + (32 << 10));                 //  8 KB
  uint4* W2F8lo = (uint4*)(ws + (40 << 10));                 //  8 KB
  u16*   vh1 = (u16*)(ws + (64 << 10));                      // 512 KB [b][r][256] f16 (v1)
  u16*   vh2 = (u16*)(ws + (64 << 10) + (512 << 10));        // 512 KB [b][c][256] f16 (v2)
  u16*   ms1 = (u16*)(ws + (64 << 10) + (4 << 20));          //  16 MB [b][h][r][c]
  u16*   ms2 = (u16*)(ws + (64 << 10) + (20 << 20));         //  16 MB [b][h][c][r]
  char*  tail= (ws + (64 << 10) + (36 << 20));
  uint4* QQ4  = (uint4*)(tail);                              //   1 MB
  uint4* KH4  = (uint4*)(tail + (1 << 20));                  // 0.5 MB
  uint4* KL4z = (uint4*)(tail + (1 << 20) + (512 << 10));    //   1 MB
  float* o1  = (float*)(tail + (3 << 20));                   //   1 MB [b][r][256]
  float* o2  = (float*)(tail + (4 << 20));                   //   1 MB [b][c][256]

  gemm_mf_pack<<<dim3(32, 33), 256, 0, stream>>>(x1, Wqv1, vh1, x2, Wkv2, vh2,
                                                 W1, W2, QQ4, KH4, KL4z,
                                                 W1Bhi, W1Blo, W2F8hi, W2F8lo);

  ms_mfma7b<<<dim3(32, 8, 2), 256, 0, stream>>>(QQ4, KH4, KL4z, cost,
                                                W1Bhi, W1Blo, W2F8hi, W2F8lo, ms1, ms2);

  softmax_all5<<<dim3(128, 2, 2), 256, 0, stream>>>(ms1, ms2, attn, vh1, vh2, o1, o2);

  gemm_mf<<<dim3(16, 32), 256, 0, stream>>>(o1, Wout1, out, o2, Wout2, out + (size_t)262144, 256, 256);
}